// Round 7
// baseline (221.890 us; speedup 1.0000x reference)
//
#include <hip/hip_runtime.h>
#include <hip/hip_bf16.h>
#include <math.h>

typedef __attribute__((ext_vector_type(4))) float f32x4;
typedef __attribute__((ext_vector_type(8))) short s16x8;
typedef __hip_bfloat16 bf16;

constexpr int TOK = 2048;   // B*S tokens
constexpr int DIM = 1024;   // hidden D
constexpr int HID = 512;    // expert inter H
constexpr int NE  = 16;     // experts
constexpr int NK  = 4;      // top-k
constexpr int NHS = 1024;   // shared inter HS
constexpr int NPAIR = TOK * NK;  // 8192 token-expert pairs

#define MFMA(a, b, c) __builtin_amdgcn_mfma_f32_16x16x32_bf16(a, b, c, 0, 0, 0)

#define GLOAD_LDS(gp, lp)                                                        \
  __builtin_amdgcn_global_load_lds(                                              \
      (const __attribute__((address_space(1))) unsigned int*)(gp),               \
      (__attribute__((address_space(3))) unsigned int*)(lp), 16, 0, 0)

// Stage a (CH*32)-row x 64-col bf16 tile into LDS. rows[i] gives the global
// row for this thread's i-th 16B chunk. LDS slot s of row r holds k-chunk
// s^(r&7): XOR swizzle applied on the per-lane GLOBAL source address; the LDS
// destination stays linear (global_load_lds requirement). 0 bank conflicts
// measured in rounds 2-6.
template <int CH>
static __device__ __forceinline__ void stage_rows(const bf16* __restrict__ src, int ld,
                                                  const int* rows, int k0, bf16* lds,
                                                  int tid) {
  int wid = tid >> 6;
#pragma unroll
  for (int i = 0; i < CH; ++i) {
    int c = i * 256 + tid;      // 16B-chunk index
    int row = c >> 3;
    int slot = c & 7;
    int j = slot ^ (row & 7);
    const bf16* g = src + (size_t)rows[i] * ld + k0 + j * 8;
    bf16* l = lds + (size_t)(i * 256 + wid * 64) * 8;  // wave-uniform base
    GLOAD_LDS(g, l);
  }
}

static __device__ __forceinline__ s16x8 frag(const bf16* lds, int row, int kc) {
  return *(const s16x8*)(lds + row * 64 + ((kc ^ (row & 7)) << 3));
}

struct bf16x4 { bf16 a, b, c, d; };

// ---------------- fused transpose+cast prep kernels ----------------
// src [R][C] fp32 -> dst [C][R] bf16, 32x32 tiles, 256 threads flat.

static __device__ __forceinline__ void tr_tile(const float* __restrict__ src,
                                               bf16* __restrict__ dst, int R, int C,
                                               int bx, int by, float t[32][33], int tid) {
  int tx = tid & 31, ty = tid >> 5;  // 32 x 8
  int c0 = bx * 32, r0 = by * 32;
#pragma unroll
  for (int i = 0; i < 32; i += 8) t[ty + i][tx] = src[(size_t)(r0 + ty + i) * C + c0 + tx];
  __syncthreads();
#pragma unroll
  for (int i = 0; i < 32; i += 8)
    dst[(size_t)(c0 + ty + i) * R + r0 + tx] = __float2bfloat16(t[tx][ty + i]);
}

__global__ __launch_bounds__(256) void prep1(const float* __restrict__ ws_in,
                                             const float* __restrict__ vs_in,
                                             const float* __restrict__ e_win,
                                             const float* __restrict__ e_vin,
                                             bf16* __restrict__ wsinT, bf16* __restrict__ vsinT,
                                             bf16* __restrict__ ewinT, bf16* __restrict__ evinT) {
  __shared__ float t[32][33];
  int bid = blockIdx.x, tid = threadIdx.x;
  if (bid < 1024) {
    tr_tile(ws_in, wsinT, DIM, NHS, bid & 31, bid >> 5, t, tid);
  } else if (bid < 2048) {
    int b = bid - 1024;
    tr_tile(vs_in, vsinT, DIM, NHS, b & 31, b >> 5, t, tid);
  } else if (bid < 10240) {
    int b = bid - 2048, e = b >> 9; b &= 511;
    tr_tile(e_win + (size_t)e * DIM * HID, ewinT + (size_t)e * DIM * HID,
            DIM, HID, b & 15, b >> 4, t, tid);
  } else {
    int b = bid - 10240, e = b >> 9; b &= 511;
    tr_tile(e_vin + (size_t)e * DIM * HID, evinT + (size_t)e * DIM * HID,
            DIM, HID, b & 15, b >> 4, t, tid);
  }
}

__global__ __launch_bounds__(256) void prep2(const float* __restrict__ ws_out,
                                             const float* __restrict__ e_wout,
                                             bf16* __restrict__ wsoutT,
                                             bf16* __restrict__ ewoutT) {
  __shared__ float t[32][33];
  int bid = blockIdx.x, tid = threadIdx.x;
  if (bid < 1024) {
    tr_tile(ws_out, wsoutT, NHS, DIM, bid & 31, bid >> 5, t, tid);
  } else {
    int b = bid - 1024, e = b >> 9; b &= 511;
    tr_tile(e_wout + (size_t)e * HID * DIM, ewoutT + (size_t)e * HID * DIM,
            HID, DIM, b & 31, b >> 5, t, tid);
  }
}

// ---------------- gate scores (fp32 exact) + x cast ----------------
// One WAVE per token; lane l owns x[16l..16l+15] (4 x float4 = full 1024-elem
// row across 64 lanes). 16 experts x 4 independent float4 w-loads + dot4;
// butterfly reduce.

__global__ __launch_bounds__(256) void gate_scores(const float* __restrict__ x,
                                                   const float* __restrict__ gw,
                                                   bf16* __restrict__ xb,
                                                   float* __restrict__ scores) {
  int lane = threadIdx.x & 63, wid = threadIdx.x >> 6;
  int t = blockIdx.x * 4 + wid;
  const float* xr = x + (size_t)t * DIM + lane * 16;
  float4 x4[4];
#pragma unroll
  for (int q = 0; q < 4; ++q) x4[q] = *(const float4*)(xr + q * 4);
  {  // cast this token's full row to bf16
    bf16* xo = xb + (size_t)t * DIM + lane * 16;
#pragma unroll
    for (int q = 0; q < 4; ++q) {
      bf16x4 o{__float2bfloat16(x4[q].x), __float2bfloat16(x4[q].y),
               __float2bfloat16(x4[q].z), __float2bfloat16(x4[q].w)};
      *reinterpret_cast<bf16x4*>(xo + q * 4) = o;
    }
  }
  float s[NE];
#pragma unroll
  for (int e = 0; e < NE; ++e) {
    const float* wr_ = gw + (size_t)e * DIM + lane * 16;
    float a = 0.f;
#pragma unroll
    for (int q = 0; q < 4; ++q) {
      float4 w4 = *(const float4*)(wr_ + q * 4);
      a += x4[q].x * w4.x + x4[q].y * w4.y + x4[q].z * w4.z + x4[q].w * w4.w;
    }
    s[e] = a;
  }
#pragma unroll
  for (int e = 0; e < NE; ++e)
#pragma unroll
    for (int off = 32; off; off >>= 1) s[e] += __shfl_xor(s[e], off);
  if (lane == 0) {
#pragma unroll
    for (int e = 0; e < NE; ++e) scores[(size_t)t * NE + e] = s[e];
  }
}

// One THREAD per token: sigmoid + top-4 + LDS histogram -> 16 atomics/block.
__global__ __launch_bounds__(256) void topk_hist(const float* __restrict__ scores,
                                                 int* __restrict__ topi,
                                                 float* __restrict__ topw,
                                                 int* __restrict__ counts) {
  __shared__ int h[NE];
  int tid = threadIdx.x;
  int t = blockIdx.x * 256 + tid;
  if (tid < NE) h[tid] = 0;
  __syncthreads();
  float g[NE];
  const float* sr = scores + (size_t)t * NE;
#pragma unroll
  for (int q = 0; q < 4; ++q) {
    float4 v = *(const float4*)(sr + q * 4);
    g[q * 4 + 0] = 1.f / (1.f + expf(-v.x));
    g[q * 4 + 1] = 1.f / (1.f + expf(-v.y));
    g[q * 4 + 2] = 1.f / (1.f + expf(-v.z));
    g[q * 4 + 3] = 1.f / (1.f + expf(-v.w));
  }
  unsigned used = 0;
  int bi[NK]; float bv[NK];
  float sum = 0.f;
#pragma unroll
  for (int j = 0; j < NK; ++j) {        // lax.top_k tie-break: lowest index first
    int best = 0; float v = -1e30f;
#pragma unroll
    for (int e = 0; e < NE; ++e)
      if (!((used >> e) & 1u) && g[e] > v) { v = g[e]; best = e; }
    used |= 1u << best; bi[j] = best; bv[j] = v; sum += v;
  }
  float inv = 1.f / sum;
#pragma unroll
  for (int j = 0; j < NK; ++j) {
    topi[t * NK + j] = bi[j];
    topw[t * NK + j] = bv[j] * inv;
    atomicAdd(&h[bi[j]], 1);
  }
  __syncthreads();
  if (tid < NE) atomicAdd(&counts[tid], h[tid]);
}

// Tiny serial kernel: offsets, segment lists, cursor reset. ~500 scalar ops.
__global__ __launch_bounds__(64) void route_small(const int* __restrict__ counts,
                                                  int* __restrict__ offs,
                                                  int* __restrict__ seg_up,
                                                  int* __restrict__ nseg_up,
                                                  int* __restrict__ seg_dn,
                                                  int* __restrict__ nseg_dn,
                                                  int* __restrict__ cursor) {
  if (threadIdx.x != 0) return;
  int o = 0;
#pragma unroll
  for (int e = 0; e < NE; ++e) { offs[e] = o; cursor[e * 32] = 0; o += counts[e]; }
  int s = 0;
  for (int e = 0; e < NE; ++e)
    for (int m = 0; m < counts[e]; m += 64) seg_up[s++] = (e << 16) | m;
  nseg_up[0] = s;
  s = 0;
  for (int e = 0; e < NE; ++e)
    for (int m = 0; m < counts[e]; m += 128) seg_dn[s++] = (e << 16) | m;
  nseg_dn[0] = s;
}

// Parallel compaction: each pair takes a slot via per-expert atomic cursor
// (padded to one cacheline per expert). Slot order within an expert is
// non-deterministic but output-invariant.
__global__ __launch_bounds__(256) void scatter_pairs(const int* __restrict__ topi,
                                                     const float* __restrict__ topw,
                                                     const int* __restrict__ offs,
                                                     int* __restrict__ cursor,
                                                     int* __restrict__ tok_list,
                                                     float* __restrict__ w_list) {
  int p = blockIdx.x * 256 + threadIdx.x;
  if (p >= NPAIR) return;
  int e = topi[p];
  int rank = atomicAdd(&cursor[e * 32], 1);
  int slot = offs[e] + rank;
  tok_list[slot] = p >> 2;   // token id
  w_list[slot] = topw[p];
}

// ---------------- fused up-projection: shared + routed (2-phase pipeline) ----
// Job space: [0,256): shared 64x128 tiles (32m x 8n), K=1024.
//            [256, 256+4*nseg): routed: seg (e,m0) x 4 n-tiles, K=1024.
// Double-buffered LDS; next K-tile's global_load_lds issued BEFORE computing
// the current tile; one barrier (vmcnt drain) per K-step. (T3 min-2-phase.)

__global__ __launch_bounds__(256) void up_all(
    const bf16* __restrict__ xb, const bf16* __restrict__ wsinT,
    const bf16* __restrict__ vsinT, const bf16* __restrict__ ewinT,
    const bf16* __restrict__ evinT, const int* __restrict__ tok_list,
    const float* __restrict__ w_list, const int* __restrict__ counts,
    const int* __restrict__ offs, const int* __restrict__ seg_up,
    const int* __restrict__ nseg_up, bf16* __restrict__ hsb,
    bf16* __restrict__ hre) {
  int j = blockIdx.x;
  int nj = 256 + 4 * nseg_up[0];
  if (j >= nj) return;
  int tid = threadIdx.x, lane = tid & 63, wid = tid >> 6;
  int wr = wid >> 1, wc = wid & 1;

  bool is_shared = (j < 256);
  int m0, n0, cnt = TOK, off_e = 0;
  const bf16 *B1, *B2;
  if (is_shared) {
    m0 = (j >> 3) * 64; n0 = (j & 7) * 128;
    B1 = wsinT + (size_t)n0 * DIM;
    B2 = vsinT + (size_t)n0 * DIM;
  } else {
    int r = j - 256, seg = r >> 2;
    n0 = (r & 3) * 128;
    int sv = seg_up[seg];
    int e = sv >> 16; m0 = sv & 0xffff;
    cnt = counts[e]; off_e = offs[e];
    B1 = ewinT + (size_t)e * HID * DIM + (size_t)n0 * DIM;
    B2 = evinT + (size_t)e * HID * DIM + (size_t)n0 * DIM;
  }

  int arows[2], brows[4];
#pragma unroll
  for (int i = 0; i < 2; ++i) {
    int row = (i * 256 + tid) >> 3;  // 0..63
    arows[i] = is_shared ? (m0 + row) : tok_list[off_e + min(m0 + row, cnt - 1)];
  }
#pragma unroll
  for (int i = 0; i < 4; ++i) brows[i] = (i * 256 + tid) >> 3;  // 0..127

  __shared__ alignas(16) bf16 As[2][64 * 64], B1s[2][128 * 64], B2s[2][128 * 64];
  f32x4 acc1[2][4], acc2[2][4];
  f32x4 z4 = {0.f, 0.f, 0.f, 0.f};
#pragma unroll
  for (int mi = 0; mi < 2; ++mi)
#pragma unroll
    for (int ni = 0; ni < 4; ++ni) { acc1[mi][ni] = z4; acc2[mi][ni] = z4; }

  constexpr int NT = DIM / 64;  // 16 K-steps
  // prologue: stage tile 0
  stage_rows<2>(xb, DIM, arows, 0, As[0], tid);
  stage_rows<4>(B1, DIM, brows, 0, B1s[0], tid);
  stage_rows<4>(B2, DIM, brows, 0, B2s[0], tid);
  __syncthreads();  // drains vmcnt(0)

  for (int kt = 0; kt < NT; ++kt) {
    int cur = kt & 1;
    if (kt + 1 < NT) {  // prefetch next tile into the other buffer
      int k0 = (kt + 1) * 64;
      stage_rows<2>(xb, DIM, arows, k0, As[cur ^ 1], tid);
      stage_rows<4>(B1, DIM, brows, k0, B1s[cur ^ 1], tid);
      stage_rows<4>(B2, DIM, brows, k0, B2s[cur ^ 1], tid);
    }
#pragma unroll
    for (int ks = 0; ks < 2; ++ks) {
      int r16 = lane & 15, kc = (ks << 2) + (lane >> 4);
      s16x8 a0 = frag(As[cur], wr * 32 + r16, kc);
      s16x8 a1 = frag(As[cur], wr * 32 + 16 + r16, kc);
#pragma unroll
      for (int ni = 0; ni < 4; ++ni) {
        s16x8 b1 = frag(B1s[cur], wc * 64 + ni * 16 + r16, kc);
        s16x8 b2 = frag(B2s[cur], wc * 64 + ni * 16 + r16, kc);
        acc1[0][ni] = MFMA(a0, b1, acc1[0][ni]);
        acc1[1][ni] = MFMA(a1, b1, acc1[1][ni]);
        acc2[0][ni] = MFMA(a0, b2, acc2[0][ni]);
        acc2[1][ni] = MFMA(a1, b2, acc2[1][ni]);
      }
    }
    if (kt + 1 < NT) __syncthreads();  // drains prefetch vmcnt, protects dbuf reuse
  }
#pragma unroll
  for (int mi = 0; mi < 2; ++mi)
#pragma unroll
    for (int ni = 0; ni < 4; ++ni)
#pragma unroll
      for (int i = 0; i < 4; ++i) {
        int r = wr * 32 + mi * 16 + (lane >> 4) * 4 + i;
        int c = n0 + wc * 64 + ni * 16 + (lane & 15);
        float z = acc1[mi][ni][i], v = acc2[mi][ni][i];
        float h = z / (1.f + __expf(-z)) * v;
        if (is_shared) {
          hsb[(size_t)(m0 + r) * NHS + c] = __float2bfloat16(h);
        } else {
          int gr = m0 + r;
          if (gr < cnt)
            hre[(size_t)(off_e + gr) * HID + c] =
                __float2bfloat16(h * w_list[off_e + gr]);
        }
      }
}

// ---------------- fused down-projection: shared + routed (2-phase, atomic) ---
// out zeroed by memset; every job atomicAdds its 128x128 fp32 tile.
// Job space: [0,128): shared 128x128 (16m x 8n), K=1024.
//            [128, 128+8*nseg): routed seg x 8 n-tiles, K=512.

__global__ __launch_bounds__(256) void down_all(
    const bf16* __restrict__ hsb, const bf16* __restrict__ wsoutT,
    const bf16* __restrict__ hre, const bf16* __restrict__ ewoutT,
    const int* __restrict__ tok_list, const int* __restrict__ counts,
    const int* __restrict__ offs, const int* __restrict__ seg_dn,
    const int* __restrict__ nseg_dn, float* __restrict__ out) {
  int j = blockIdx.x;
  int nj = 128 + 8 * nseg_dn[0];
  if (j >= nj) return;
  int tid = threadIdx.x, lane = tid & 63, wid = tid >> 6;
  int wr = wid >> 1, wc = wid & 1;

  bool is_shared = (j < 128);
  int m0, n0, cnt = TOK, off_e = 0, K, ld;
  const bf16 *A, *B;
  if (is_shared) {
    m0 = (j >> 3) * 128; n0 = (j & 7) * 128;
    A = hsb; ld = NHS; K = NHS;
    B = wsoutT + (size_t)n0 * NHS;
  } else {
    int r = j - 128, seg = r >> 3;
    n0 = (r & 7) * 128;
    int sv = seg_dn[seg];
    int e = sv >> 16; m0 = sv & 0xffff;
    cnt = counts[e]; off_e = offs[e];
    A = hre + (size_t)off_e * HID; ld = HID; K = HID;
    B = ewoutT + (size_t)e * DIM * HID + (size_t)n0 * HID;
  }

  int arows[4], brows[4];
#pragma unroll
  for (int i = 0; i < 4; ++i) {
    int row = (i * 256 + tid) >> 3;  // 0..127
    arows[i] = is_shared ? (m0 + row) : min(m0 + row, cnt - 1);
    brows[i] = row;
  }

  __shared__ alignas(16) bf16 As[2][128 * 64], Bs[2][128 * 64];
  f32x4 acc[4][4];
  f32x4 z4 = {0.f, 0.f, 0.f, 0.f};
#pragma unroll
  for (int mi = 0; mi < 4; ++mi)
#pragma unroll
    for (int ni = 0; ni < 4; ++ni) acc[mi][ni] = z4;

  int NT = K / 64;
  stage_rows<4>(A, ld, arows, 0, As[0], tid);
  stage_rows<4>(B, ld, brows, 0, Bs[0], tid);
  __syncthreads();

  for (int kt = 0; kt < NT; ++kt) {
    int cur = kt & 1;
    if (kt + 1 < NT) {
      int k0 = (kt + 1) * 64;
      stage_rows<4>(A, ld, arows, k0, As[cur ^ 1], tid);
      stage_rows<4>(B, ld, brows, k0, Bs[cur ^ 1], tid);
    }
#pragma unroll
    for (int ks = 0; ks < 2; ++ks) {
      int r16 = lane & 15, kc = (ks << 2) + (lane >> 4);
      s16x8 a[4];
#pragma unroll
      for (int mi = 0; mi < 4; ++mi) a[mi] = frag(As[cur], wr * 64 + mi * 16 + r16, kc);
#pragma unroll
      for (int ni = 0; ni < 4; ++ni) {
        s16x8 b = frag(Bs[cur], wc * 64 + ni * 16 + r16, kc);
#pragma unroll
        for (int mi = 0; mi < 4; ++mi) acc[mi][ni] = MFMA(a[mi], b, acc[mi][ni]);
      }
    }
    if (kt + 1 < NT) __syncthreads();
  }
#pragma unroll
  for (int mi = 0; mi < 4; ++mi)
#pragma unroll
    for (int ni = 0; ni < 4; ++ni)
#pragma unroll
      for (int i = 0; i < 4; ++i) {
        int r = wr * 64 + mi * 16 + (lane >> 4) * 4 + i;
        int c = n0 + wc * 64 + ni * 16 + (lane & 15);
        if (is_shared) {
          atomicAdd(&out[(size_t)(m0 + r) * DIM + c], acc[mi][ni][i]);
        } else {
          int gr = m0 + r;
          if (gr < cnt)
            atomicAdd(&out[(size_t)tok_list[off_e + gr] * DIM + c], acc[mi][ni][i]);
        }
      }
}

// ---------------- launcher ----------------

extern "C" void kernel_launch(void* const* d_in, const int* in_sizes, int n_in,
                              void* d_out, int out_size, void* d_ws, size_t ws_size,
                              hipStream_t stream) {
  const float* x      = (const float*)d_in[0];
  const float* gw     = (const float*)d_in[1];
  const float* ws_in  = (const float*)d_in[2];
  const float* vs_in  = (const float*)d_in[3];
  const float* ws_out = (const float*)d_in[4];
  const float* e_win  = (const float*)d_in[5];
  const float* e_vin  = (const float*)d_in[6];
  const float* e_wout = (const float*)d_in[7];
  float* out = (float*)d_out;

  // Workspace layout, peak ~52.7 MB (validated fits in rounds 2-6).
  char* p = (char*)d_ws;
  bf16* xb     = (bf16*)p;  p += (size_t)TOK * DIM * 2;            // 4 MB
  bf16* wsinT  = (bf16*)p;                                         // 2 MB
  bf16* wsoutT = wsinT;                                            // reused after up_all
  p += (size_t)NHS * DIM * 2;
  bf16* vsinT  = (bf16*)p;  p += (size_t)NHS * DIM * 2;            // 2 MB
  bf16* hsb    = (bf16*)p;  p += (size_t)TOK * NHS * 2;            // 4 MB
  bf16* ewinT  = (bf16*)p;                                         // 16 MB
  bf16* ewoutT = ewinT;                                            // reused after up_all
  p += (size_t)NE * DIM * HID * 2;
  bf16* evinT  = (bf16*)p;  p += (size_t)NE * DIM * HID * 2;       // 16 MB
  bf16* hre    = (bf16*)p;  p += (size_t)(NPAIR + 128) * HID * 2;  // 8.25 MB
  int*   topi     = (int*)p;    p += (size_t)NPAIR * 4;
  float* topw     = (float*)p;  p += (size_t)NPAIR * 4;
  int*   tok_list = (int*)p;    p += (size_t)NPAIR * 4;
  float* w_list   = (float*)p;  p += (size_t)NPAIR * 4;
  float* scores   = (float*)p;  p += (size_t)TOK * NE * 4;         // 128 KB
  int*   counts   = (int*)p;    p += 64;
  int*   offs     = (int*)p;    p += 64;
  int*   cursor   = (int*)p;    p += NE * 32 * 4;                  // 1 line/expert
  int*   seg_up   = (int*)p;    p += 256 * 4;   // worst case 144 segs
  int*   nseg_up  = (int*)p;    p += 64;
  int*   seg_dn   = (int*)p;    p += 128 * 4;   // worst case 80 segs
  int*   nseg_dn  = (int*)p;    p += 64;

  hipMemsetAsync(counts, 0, NE * sizeof(int), stream);
  gate_scores<<<TOK / 4, 256, 0, stream>>>(x, gw, xb, scores);
  topk_hist<<<TOK / 256, 256, 0, stream>>>(scores, topi, topw, counts);
  route_small<<<1, 64, 0, stream>>>(counts, offs, seg_up, nseg_up,
                                    seg_dn, nseg_dn, cursor);
  scatter_pairs<<<NPAIR / 256, 256, 0, stream>>>(topi, topw, offs, cursor,
                                                 tok_list, w_list);

  prep1<<<18432, 256, 0, stream>>>(ws_in, vs_in, e_win, e_vin,
                                   wsinT, vsinT, ewinT, evinT);

  // max jobs: 256 shared + 4 * 144 worst-case segs = 832
  up_all<<<832, 256, 0, stream>>>(xb, wsinT, vsinT, ewinT, evinT, tok_list,
                                  w_list, counts, offs, seg_up, nseg_up, hsb, hre);

  // ws_out/e_wout transposes overwrite wsinT/ewinT (dead after up_all).
  prep2<<<9216, 256, 0, stream>>>(ws_out, e_wout, wsoutT, ewoutT);

  hipMemsetAsync(out, 0, (size_t)TOK * DIM * 4, stream);
  down_all<<<768, 256, 0, stream>>>(hsb, wsoutT, hre, ewoutT, tok_list, counts,
                                    offs, seg_dn, nseg_dn, out);
}

// Round 8
// 166.035 us; speedup vs baseline: 1.3364x; 1.3364x over previous
//
#include <hip/hip_runtime.h>
#include <hip/hip_bf16.h>
#include <math.h>

typedef __attribute__((ext_vector_type(4))) float f32x4;
typedef __attribute__((ext_vector_type(8))) short s16x8;
typedef __hip_bfloat16 bf16;

constexpr int TOK = 2048;   // B*S tokens
constexpr int DIM = 1024;   // hidden D
constexpr int HID = 512;    // expert inter H
constexpr int NE  = 16;     // experts
constexpr int NK  = 4;      // top-k
constexpr int NHS = 1024;   // shared inter HS
constexpr int NPAIR = TOK * NK;  // 8192 token-expert pairs

// GEMM grids: 128-row segs worst case sum(ceil(cnt_e/128)) <= 16 + 8192/128 = 80
constexpr int UP_GRID = 128 + 4 * 80;  // 448 (mult of 8)
constexpr int DN_GRID = 64 + 4 * 80;   // 384 (mult of 8)

#define MFMA(a, b, c) __builtin_amdgcn_mfma_f32_16x16x32_bf16(a, b, c, 0, 0, 0)

#define GLOAD_LDS(gp, lp)                                                        \
  __builtin_amdgcn_global_load_lds(                                              \
      (const __attribute__((address_space(1))) unsigned int*)(gp),               \
      (__attribute__((address_space(3))) unsigned int*)(lp), 16, 0, 0)

// Stage a (CH*64)-row x 64-col bf16 tile into LDS with 512 threads. rp[i] is
// this thread's precomputed row base pointer (already includes row*ld and any
// gather/interleave). LDS slot s of row r holds k-chunk s^(r&7): XOR swizzle
// applied on the per-lane GLOBAL source; LDS dest stays linear
// (global_load_lds requirement). 0 bank conflicts measured rounds 2-7.
template <int CH>
static __device__ __forceinline__ void stage_p(const bf16* const* rp, int k0,
                                               bf16* lds, int tid) {
  int wid = tid >> 6;
#pragma unroll
  for (int i = 0; i < CH; ++i) {
    int c = i * 512 + tid;      // 16B-chunk index
    int row = c >> 3;
    int slot = c & 7;
    int j = slot ^ (row & 7);
    const bf16* g = rp[i] + k0 + j * 8;
    bf16* l = lds + (size_t)(i * 512 + wid * 64) * 8;  // wave-uniform base
    GLOAD_LDS(g, l);
  }
}

static __device__ __forceinline__ s16x8 frag(const bf16* lds, int row, int kc) {
  return *(const s16x8*)(lds + row * 64 + ((kc ^ (row & 7)) << 3));
}

struct bf16x4 { bf16 a, b, c, d; };

// ---------------- fused transpose+cast prep kernels ----------------
// src [R][C] fp32 -> dst [C][R] bf16, 32x32 tiles, 256 threads flat.

static __device__ __forceinline__ void tr_tile(const float* __restrict__ src,
                                               bf16* __restrict__ dst, int R, int C,
                                               int bx, int by, float t[32][33], int tid) {
  int tx = tid & 31, ty = tid >> 5;  // 32 x 8
  int c0 = bx * 32, r0 = by * 32;
#pragma unroll
  for (int i = 0; i < 32; i += 8) t[ty + i][tx] = src[(size_t)(r0 + ty + i) * C + c0 + tx];
  __syncthreads();
#pragma unroll
  for (int i = 0; i < 32; i += 8)
    dst[(size_t)(c0 + ty + i) * R + r0 + tx] = __float2bfloat16(t[tx][ty + i]);
}

__global__ __launch_bounds__(256) void prep1(const float* __restrict__ ws_in,
                                             const float* __restrict__ vs_in,
                                             const float* __restrict__ e_win,
                                             const float* __restrict__ e_vin,
                                             bf16* __restrict__ wsinT, bf16* __restrict__ vsinT,
                                             bf16* __restrict__ ewinT, bf16* __restrict__ evinT) {
  __shared__ float t[32][33];
  int bid = blockIdx.x, tid = threadIdx.x;
  if (bid < 1024) {
    tr_tile(ws_in, wsinT, DIM, NHS, bid & 31, bid >> 5, t, tid);
  } else if (bid < 2048) {
    int b = bid - 1024;
    tr_tile(vs_in, vsinT, DIM, NHS, b & 31, b >> 5, t, tid);
  } else if (bid < 10240) {
    int b = bid - 2048, e = b >> 9; b &= 511;
    tr_tile(e_win + (size_t)e * DIM * HID, ewinT + (size_t)e * DIM * HID,
            DIM, HID, b & 15, b >> 4, t, tid);
  } else {
    int b = bid - 10240, e = b >> 9; b &= 511;
    tr_tile(e_vin + (size_t)e * DIM * HID, evinT + (size_t)e * DIM * HID,
            DIM, HID, b & 15, b >> 4, t, tid);
  }
}

__global__ __launch_bounds__(256) void prep2(const float* __restrict__ ws_out,
                                             const float* __restrict__ e_wout,
                                             bf16* __restrict__ wsoutT,
                                             bf16* __restrict__ ewoutT) {
  __shared__ float t[32][33];
  int bid = blockIdx.x, tid = threadIdx.x;
  if (bid < 1024) {
    tr_tile(ws_out, wsoutT, NHS, DIM, bid & 31, bid >> 5, t, tid);
  } else {
    int b = bid - 1024, e = b >> 9; b &= 511;
    tr_tile(e_wout + (size_t)e * HID * DIM, ewoutT + (size_t)e * HID * DIM,
            HID, DIM, b & 31, b >> 5, t, tid);
  }
}

// ---------------- gate scores (fp32 exact) + x cast ----------------
// One WAVE per token; lane l owns x[16l..16l+15].

__global__ __launch_bounds__(256) void gate_scores(const float* __restrict__ x,
                                                   const float* __restrict__ gw,
                                                   bf16* __restrict__ xb,
                                                   float* __restrict__ scores) {
  int lane = threadIdx.x & 63, wid = threadIdx.x >> 6;
  int t = blockIdx.x * 4 + wid;
  const float* xr = x + (size_t)t * DIM + lane * 16;
  float4 x4[4];
#pragma unroll
  for (int q = 0; q < 4; ++q) x4[q] = *(const float4*)(xr + q * 4);
  {  // cast this token's full row to bf16
    bf16* xo = xb + (size_t)t * DIM + lane * 16;
#pragma unroll
    for (int q = 0; q < 4; ++q) {
      bf16x4 o{__float2bfloat16(x4[q].x), __float2bfloat16(x4[q].y),
               __float2bfloat16(x4[q].z), __float2bfloat16(x4[q].w)};
      *reinterpret_cast<bf16x4*>(xo + q * 4) = o;
    }
  }
  float s[NE];
#pragma unroll
  for (int e = 0; e < NE; ++e) {
    const float* wr_ = gw + (size_t)e * DIM + lane * 16;
    float a = 0.f;
#pragma unroll
    for (int q = 0; q < 4; ++q) {
      float4 w4 = *(const float4*)(wr_ + q * 4);
      a += x4[q].x * w4.x + x4[q].y * w4.y + x4[q].z * w4.z + x4[q].w * w4.w;
    }
    s[e] = a;
  }
#pragma unroll
  for (int e = 0; e < NE; ++e)
#pragma unroll
    for (int off = 32; off; off >>= 1) s[e] += __shfl_xor(s[e], off);
  if (lane == 0) {
#pragma unroll
    for (int e = 0; e < NE; ++e) scores[(size_t)t * NE + e] = s[e];
  }
}

// One THREAD per token: sigmoid + top-4 + LDS histogram -> 16 atomics/block.
__global__ __launch_bounds__(256) void topk_hist(const float* __restrict__ scores,
                                                 int* __restrict__ topi,
                                                 float* __restrict__ topw,
                                                 int* __restrict__ counts) {
  __shared__ int h[NE];
  int tid = threadIdx.x;
  int t = blockIdx.x * 256 + tid;
  if (tid < NE) h[tid] = 0;
  __syncthreads();
  float g[NE];
  const float* sr = scores + (size_t)t * NE;
#pragma unroll
  for (int q = 0; q < 4; ++q) {
    float4 v = *(const float4*)(sr + q * 4);
    g[q * 4 + 0] = 1.f / (1.f + expf(-v.x));
    g[q * 4 + 1] = 1.f / (1.f + expf(-v.y));
    g[q * 4 + 2] = 1.f / (1.f + expf(-v.z));
    g[q * 4 + 3] = 1.f / (1.f + expf(-v.w));
  }
  unsigned used = 0;
  int bi[NK]; float bv[NK];
  float sum = 0.f;
#pragma unroll
  for (int j = 0; j < NK; ++j) {        // lax.top_k tie-break: lowest index first
    int best = 0; float v = -1e30f;
#pragma unroll
    for (int e = 0; e < NE; ++e)
      if (!((used >> e) & 1u) && g[e] > v) { v = g[e]; best = e; }
    used |= 1u << best; bi[j] = best; bv[j] = v; sum += v;
  }
  float inv = 1.f / sum;
#pragma unroll
  for (int j = 0; j < NK; ++j) {
    topi[t * NK + j] = bi[j];
    topw[t * NK + j] = bv[j] * inv;
    atomicAdd(&h[bi[j]], 1);
  }
  __syncthreads();
  if (tid < NE) atomicAdd(&counts[tid], h[tid]);
}

// Tiny serial kernel: offsets, 128-row segment list, cursor reset.
__global__ __launch_bounds__(64) void route_small(const int* __restrict__ counts,
                                                  int* __restrict__ offs,
                                                  int* __restrict__ segs,
                                                  int* __restrict__ nseg,
                                                  int* __restrict__ cursor) {
  if (threadIdx.x != 0) return;
  int o = 0;
#pragma unroll
  for (int e = 0; e < NE; ++e) { offs[e] = o; cursor[e * 32] = 0; o += counts[e]; }
  int s = 0;
  for (int e = 0; e < NE; ++e)
    for (int m = 0; m < counts[e]; m += 128) segs[s++] = (e << 16) | m;
  nseg[0] = s;
}

// Parallel compaction via per-expert atomic cursor (cacheline-padded).
__global__ __launch_bounds__(256) void scatter_pairs(const int* __restrict__ topi,
                                                     const float* __restrict__ topw,
                                                     const int* __restrict__ offs,
                                                     int* __restrict__ cursor,
                                                     int* __restrict__ tok_list,
                                                     float* __restrict__ w_list) {
  int p = blockIdx.x * 256 + threadIdx.x;
  if (p >= NPAIR) return;
  int e = topi[p];
  int rank = atomicAdd(&cursor[e * 32], 1);
  int slot = offs[e] + rank;
  tok_list[slot] = p >> 2;   // token id
  w_list[slot] = topw[p];
}

// ---------------- fused up-projection: shared + routed ----------------
// 128x256 tile, 8 waves (2Mx4N, each 64x64), 48 KB LDS, single-buffered
// 2-barrier K-loop (round-6-proven schedule). B' operand interleaves W1/W2
// rows 16-at-a-time: B'-row group [32i..32i+15]=W1 rows, [32i+16..32i+31]=W2
// rows for the same 16 output cols -> z and v land in adjacent n-frags
// (acc[m][q], acc[m][q+1]) of the SAME wave; epilogue pairs them locally.
// Job space: [0,128): shared (16 m x 8 n'), K=1024.
//            [128, 128+4*nseg): routed seg x 4 n'-tiles, K=1024.

__global__ __launch_bounds__(512, 4) void up_all(
    const bf16* __restrict__ xb, const bf16* __restrict__ wsinT,
    const bf16* __restrict__ vsinT, const bf16* __restrict__ ewinT,
    const bf16* __restrict__ evinT, const int* __restrict__ tok_list,
    const float* __restrict__ w_list, const int* __restrict__ counts,
    const int* __restrict__ offs, const int* __restrict__ segs,
    const int* __restrict__ nseg, bf16* __restrict__ hsb,
    bf16* __restrict__ hre) {
  int bid = blockIdx.x;
  int j = (bid & 7) * (UP_GRID / 8) + (bid >> 3);  // XCD-chunked job swizzle
  int nj = 128 + 4 * nseg[0];
  if (j >= nj) return;
  int tid = threadIdx.x, lane = tid & 63, wid = tid >> 6;
  int wr = wid >> 2, wc = wid & 3;

  bool is_shared = (j < 128);
  int m0, n0, cnt = TOK, off_e = 0;
  const bf16 *w1, *w2;
  if (is_shared) {
    m0 = (j >> 3) * 128; n0 = j & 7;
    w1 = wsinT; w2 = vsinT;
  } else {
    int r = j - 128;
    int sv = segs[r >> 2]; n0 = r & 3;
    int e = sv >> 16; m0 = sv & 0xffff;
    cnt = counts[e]; off_e = offs[e];
    w1 = ewinT + (size_t)e * HID * DIM;
    w2 = evinT + (size_t)e * HID * DIM;
  }

  const bf16* ap[2]; const bf16* bp[4];
#pragma unroll
  for (int i = 0; i < 2; ++i) {
    int row = (i * 512 + tid) >> 3;  // 0..127
    int gr = is_shared ? (m0 + row) : tok_list[off_e + min(m0 + row, cnt - 1)];
    ap[i] = xb + (size_t)gr * DIM;
  }
#pragma unroll
  for (int i = 0; i < 4; ++i) {
    int r = (i * 512 + tid) >> 3;    // B'-row 0..255
    int ridx = n0 * 128 + (r >> 5) * 16 + (r & 15);
    bp[i] = ((r & 16) ? w2 : w1) + (size_t)ridx * DIM;
  }

  __shared__ alignas(16) bf16 As[128 * 64], Bs[256 * 64];
  f32x4 acc[4][4];
  f32x4 z4 = {0.f, 0.f, 0.f, 0.f};
#pragma unroll
  for (int m = 0; m < 4; ++m)
#pragma unroll
    for (int q = 0; q < 4; ++q) acc[m][q] = z4;

  for (int k0 = 0; k0 < DIM; k0 += 64) {
    __syncthreads();
    stage_p<2>(ap, k0, As, tid);
    stage_p<4>(bp, k0, Bs, tid);
    __syncthreads();
#pragma unroll
    for (int ks = 0; ks < 2; ++ks) {
      int r16 = lane & 15, kc = (ks << 2) + (lane >> 4);
      s16x8 a[4];
#pragma unroll
      for (int m = 0; m < 4; ++m) a[m] = frag(As, wr * 64 + m * 16 + r16, kc);
#pragma unroll
      for (int q = 0; q < 4; ++q) {
        s16x8 b = frag(Bs, wc * 64 + q * 16 + r16, kc);
#pragma unroll
        for (int m = 0; m < 4; ++m) acc[m][q] = MFMA(a[m], b, acc[m][q]);
      }
    }
  }
#pragma unroll
  for (int m = 0; m < 4; ++m)
#pragma unroll
    for (int q = 0; q < 4; q += 2) {
      int c = n0 * 128 + (wc * 2 + (q >> 1)) * 16 + (lane & 15);
#pragma unroll
      for (int i = 0; i < 4; ++i) {
        int r = wr * 64 + m * 16 + (lane >> 4) * 4 + i;
        float z = acc[m][q][i], v = acc[m][q + 1][i];
        float h = z / (1.f + __expf(-z)) * v;
        if (is_shared) {
          hsb[(size_t)(m0 + r) * NHS + c] = __float2bfloat16(h);
        } else {
          int gr = m0 + r;
          if (gr < cnt)
            hre[(size_t)(off_e + gr) * HID + c] =
                __float2bfloat16(h * w_list[off_e + gr]);
        }
      }
    }
}

// ---------------- fused down-projection: shared + routed (all-atomic) --------
// 128x256 tile, 8 waves, 48 KB LDS, single-buffered 2-barrier loop.
// Job space: [0,64): shared (16 m x 4 n), K=1024.
//            [64, 64+4*nseg): routed seg x 4 n-tiles, K=512.

__global__ __launch_bounds__(512, 4) void down_all(
    const bf16* __restrict__ hsb, const bf16* __restrict__ wsoutT,
    const bf16* __restrict__ hre, const bf16* __restrict__ ewoutT,
    const int* __restrict__ tok_list, const int* __restrict__ counts,
    const int* __restrict__ offs, const int* __restrict__ segs,
    const int* __restrict__ nseg, float* __restrict__ out) {
  int bid = blockIdx.x;
  int j = (bid & 7) * (DN_GRID / 8) + (bid >> 3);
  int nj = 64 + 4 * nseg[0];
  if (j >= nj) return;
  int tid = threadIdx.x, lane = tid & 63, wid = tid >> 6;
  int wr = wid >> 2, wc = wid & 3;

  bool is_shared = (j < 64);
  int m0, n0, cnt = TOK, off_e = 0, K, ldA, ldB;
  const bf16 *Abase, *Bbase;
  if (is_shared) {
    m0 = (j >> 2) * 128; n0 = j & 3;
    Abase = hsb; ldA = NHS; K = NHS;
    Bbase = wsoutT; ldB = NHS;
  } else {
    int r = j - 64;
    int sv = segs[r >> 2]; n0 = r & 3;
    int e = sv >> 16; m0 = sv & 0xffff;
    cnt = counts[e]; off_e = offs[e];
    Abase = hre + (size_t)off_e * HID; ldA = HID; K = HID;
    Bbase = ewoutT + (size_t)e * DIM * HID; ldB = HID;
  }

  const bf16* ap[2]; const bf16* bp[4];
#pragma unroll
  for (int i = 0; i < 2; ++i) {
    int row = (i * 512 + tid) >> 3;  // 0..127
    int gr = is_shared ? (m0 + row) : min(m0 + row, cnt - 1);
    ap[i] = Abase + (size_t)gr * ldA;
  }
#pragma unroll
  for (int i = 0; i < 4; ++i) {
    int r = (i * 512 + tid) >> 3;    // 0..255
    bp[i] = Bbase + (size_t)(n0 * 256 + r) * ldB;
  }

  __shared__ alignas(16) bf16 As[128 * 64], Bs[256 * 64];
  f32x4 acc[4][4];
  f32x4 z4 = {0.f, 0.f, 0.f, 0.f};
#pragma unroll
  for (int m = 0; m < 4; ++m)
#pragma unroll
    for (int q = 0; q < 4; ++q) acc[m][q] = z4;

  int NT = K / 64;
  for (int kt = 0; kt < NT; ++kt) {
    int k0 = kt * 64;
    __syncthreads();
    stage_p<2>(ap, k0, As, tid);
    stage_p<4>(bp, k0, Bs, tid);
    __syncthreads();
#pragma unroll
    for (int ks = 0; ks < 2; ++ks) {
      int r16 = lane & 15, kc = (ks << 2) + (lane >> 4);
      s16x8 a[4];
#pragma unroll
      for (int m = 0; m < 4; ++m) a[m] = frag(As, wr * 64 + m * 16 + r16, kc);
#pragma unroll
      for (int q = 0; q < 4; ++q) {
        s16x8 b = frag(Bs, wc * 64 + q * 16 + r16, kc);
#pragma unroll
        for (int m = 0; m < 4; ++m) acc[m][q] = MFMA(a[m], b, acc[m][q]);
      }
    }
  }
#pragma unroll
  for (int m = 0; m < 4; ++m)
#pragma unroll
    for (int q = 0; q < 4; ++q) {
      int c = n0 * 256 + wc * 64 + q * 16 + (lane & 15);
#pragma unroll
      for (int i = 0; i < 4; ++i) {
        int r = wr * 64 + m * 16 + (lane >> 4) * 4 + i;
        if (is_shared) {
          atomicAdd(&out[(size_t)(m0 + r) * DIM + c], acc[m][q][i]);
        } else {
          int gr = m0 + r;
          if (gr < cnt)
            atomicAdd(&out[(size_t)tok_list[off_e + gr] * DIM + c], acc[m][q][i]);
        }
      }
    }
}

// ---------------- launcher ----------------

extern "C" void kernel_launch(void* const* d_in, const int* in_sizes, int n_in,
                              void* d_out, int out_size, void* d_ws, size_t ws_size,
                              hipStream_t stream) {
  const float* x      = (const float*)d_in[0];
  const float* gw     = (const float*)d_in[1];
  const float* ws_in  = (const float*)d_in[2];
  const float* vs_in  = (const float*)d_in[3];
  const float* ws_out = (const float*)d_in[4];
  const float* e_win  = (const float*)d_in[5];
  const float* e_vin  = (const float*)d_in[6];
  const float* e_wout = (const float*)d_in[7];
  float* out = (float*)d_out;

  // Workspace layout, peak ~52.7 MB (validated fits in rounds 2-7).
  char* p = (char*)d_ws;
  bf16* xb     = (bf16*)p;  p += (size_t)TOK * DIM * 2;            // 4 MB
  bf16* wsinT  = (bf16*)p;                                         // 2 MB
  bf16* wsoutT = wsinT;                                            // reused after up_all
  p += (size_t)NHS * DIM * 2;
  bf16* vsinT  = (bf16*)p;  p += (size_t)NHS * DIM * 2;            // 2 MB
  bf16* hsb    = (bf16*)p;  p += (size_t)TOK * NHS * 2;            // 4 MB
  bf16* ewinT  = (bf16*)p;                                         // 16 MB
  bf16* ewoutT = ewinT;                                            // reused after up_all
  p += (size_t)NE * DIM * HID * 2;
  bf16* evinT  = (bf16*)p;  p += (size_t)NE * DIM * HID * 2;       // 16 MB
  bf16* hre    = (bf16*)p;  p += (size_t)(NPAIR + 128) * HID * 2;  // 8.25 MB
  int*   topi     = (int*)p;    p += (size_t)NPAIR * 4;
  float* topw     = (float*)p;  p += (size_t)NPAIR * 4;
  int*   tok_list = (int*)p;    p += (size_t)NPAIR * 4;
  float* w_list   = (float*)p;  p += (size_t)NPAIR * 4;
  float* scores   = (float*)p;  p += (size_t)TOK * NE * 4;         // 128 KB
  int*   counts   = (int*)p;    p += 64;
  int*   offs     = (int*)p;    p += 64;
  int*   cursor   = (int*)p;    p += NE * 32 * 4;                  // 1 line/expert
  int*   segs     = (int*)p;    p += 128 * 4;   // worst case 80 segs
  int*   nseg     = (int*)p;    p += 64;

  hipMemsetAsync(counts, 0, NE * sizeof(int), stream);
  gate_scores<<<TOK / 4, 256, 0, stream>>>(x, gw, xb, scores);
  topk_hist<<<TOK / 256, 256, 0, stream>>>(scores, topi, topw, counts);
  route_small<<<1, 64, 0, stream>>>(counts, offs, segs, nseg, cursor);
  scatter_pairs<<<NPAIR / 256, 256, 0, stream>>>(topi, topw, offs, cursor,
                                                 tok_list, w_list);

  prep1<<<18432, 256, 0, stream>>>(ws_in, vs_in, e_win, e_vin,
                                   wsinT, vsinT, ewinT, evinT);

  up_all<<<UP_GRID, 512, 0, stream>>>(xb, wsinT, vsinT, ewinT, evinT, tok_list,
                                      w_list, counts, offs, segs, nseg, hsb, hre);

  // ws_out/e_wout transposes overwrite wsinT/ewinT (dead after up_all).
  prep2<<<9216, 256, 0, stream>>>(ws_out, e_wout, wsoutT, ewoutT);

  hipMemsetAsync(out, 0, (size_t)TOK * DIM * 4, stream);
  down_all<<<DN_GRID, 512, 0, stream>>>(hsb, wsoutT, hre, ewoutT, tok_list,
                                        counts, offs, segs, nseg, out);
}

// Round 9
// 143.822 us; speedup vs baseline: 1.5428x; 1.1544x over previous
//
#include <hip/hip_runtime.h>
#include <hip/hip_bf16.h>
#include <math.h>

typedef __attribute__((ext_vector_type(4))) float f32x4;
typedef __attribute__((ext_vector_type(8))) short s16x8;
typedef __hip_bfloat16 bf16;

constexpr int TOK = 2048;   // B*S tokens
constexpr int DIM = 1024;   // hidden D
constexpr int HID = 512;    // expert inter H
constexpr int NE  = 16;     // experts
constexpr int NK  = 4;      // top-k
constexpr int NHS = 1024;   // shared inter HS
constexpr int NPAIR = TOK * NK;  // 8192 token-expert pairs

// GEMM grids: 128-row segs worst case sum(ceil(cnt_e/128)) <= 16 + 8192/128 = 80
constexpr int UP_GRID = 128 + 4 * 80;  // 448 (mult of 8)
constexpr int DN_GRID = 64 + 4 * 80;   // 384 (mult of 8)

#define MFMA(a, b, c) __builtin_amdgcn_mfma_f32_16x16x32_bf16(a, b, c, 0, 0, 0)

#define GLOAD_LDS(gp, lp)                                                        \
  __builtin_amdgcn_global_load_lds(                                              \
      (const __attribute__((address_space(1))) unsigned int*)(gp),               \
      (__attribute__((address_space(3))) unsigned int*)(lp), 16, 0, 0)

// Stage a (CH*64)-row x 64-col bf16 tile into LDS with 512 threads. rp[i] is
// this thread's precomputed row base pointer. LDS slot s of row r holds
// k-chunk s^(r&7): XOR swizzle on the per-lane GLOBAL source; LDS dest linear
// (global_load_lds requirement). 0 bank conflicts measured rounds 2-8.
template <int CH>
static __device__ __forceinline__ void stage_p(const bf16* const* rp, int k0,
                                               bf16* lds, int tid) {
  int wid = tid >> 6;
#pragma unroll
  for (int i = 0; i < CH; ++i) {
    int c = i * 512 + tid;      // 16B-chunk index
    int row = c >> 3;
    int slot = c & 7;
    int j = slot ^ (row & 7);
    const bf16* g = rp[i] + k0 + j * 8;
    bf16* l = lds + (size_t)(i * 512 + wid * 64) * 8;  // wave-uniform base
    GLOAD_LDS(g, l);
  }
}

static __device__ __forceinline__ s16x8 frag(const bf16* lds, int row, int kc) {
  return *(const s16x8*)(lds + row * 64 + ((kc ^ (row & 7)) << 3));
}

static __device__ __forceinline__ float b2f(short u) {
  union { unsigned int i; float f; } c;
  c.i = ((unsigned int)(unsigned short)u) << 16;
  return c.f;
}

struct bf16x4 { bf16 a, b, c, d; };

// ---------------- fused transpose+cast prep kernels ----------------

static __device__ __forceinline__ void tr_tile(const float* __restrict__ src,
                                               bf16* __restrict__ dst, int R, int C,
                                               int bx, int by, float t[32][33], int tid) {
  int tx = tid & 31, ty = tid >> 5;  // 32 x 8
  int c0 = bx * 32, r0 = by * 32;
#pragma unroll
  for (int i = 0; i < 32; i += 8) t[ty + i][tx] = src[(size_t)(r0 + ty + i) * C + c0 + tx];
  __syncthreads();
#pragma unroll
  for (int i = 0; i < 32; i += 8)
    dst[(size_t)(c0 + ty + i) * R + r0 + tx] = __float2bfloat16(t[tx][ty + i]);
}

__global__ __launch_bounds__(256) void prep1(const float* __restrict__ ws_in,
                                             const float* __restrict__ vs_in,
                                             const float* __restrict__ e_win,
                                             const float* __restrict__ e_vin,
                                             bf16* __restrict__ wsinT, bf16* __restrict__ vsinT,
                                             bf16* __restrict__ ewinT, bf16* __restrict__ evinT) {
  __shared__ float t[32][33];
  int bid = blockIdx.x, tid = threadIdx.x;
  if (bid < 1024) {
    tr_tile(ws_in, wsinT, DIM, NHS, bid & 31, bid >> 5, t, tid);
  } else if (bid < 2048) {
    int b = bid - 1024;
    tr_tile(vs_in, vsinT, DIM, NHS, b & 31, b >> 5, t, tid);
  } else if (bid < 10240) {
    int b = bid - 2048, e = b >> 9; b &= 511;
    tr_tile(e_win + (size_t)e * DIM * HID, ewinT + (size_t)e * DIM * HID,
            DIM, HID, b & 15, b >> 4, t, tid);
  } else {
    int b = bid - 10240, e = b >> 9; b &= 511;
    tr_tile(e_vin + (size_t)e * DIM * HID, evinT + (size_t)e * DIM * HID,
            DIM, HID, b & 15, b >> 4, t, tid);
  }
}

__global__ __launch_bounds__(256) void prep2(const float* __restrict__ ws_out,
                                             const float* __restrict__ e_wout,
                                             bf16* __restrict__ wsoutT,
                                             bf16* __restrict__ ewoutT) {
  __shared__ float t[32][33];
  int bid = blockIdx.x, tid = threadIdx.x;
  if (bid < 1024) {
    tr_tile(ws_out, wsoutT, NHS, DIM, bid & 31, bid >> 5, t, tid);
  } else {
    int b = bid - 1024, e = b >> 9; b &= 511;
    tr_tile(e_wout + (size_t)e * HID * DIM, ewoutT + (size_t)e * HID * DIM,
            HID, DIM, b & 31, b >> 5, t, tid);
  }
}

// ---------------- gate scores (fp32 exact) + x cast ----------------
// One WAVE per token; lane l owns x[16l..16l+15].

__global__ __launch_bounds__(256) void gate_scores(const float* __restrict__ x,
                                                   const float* __restrict__ gw,
                                                   bf16* __restrict__ xb,
                                                   float* __restrict__ scores) {
  int lane = threadIdx.x & 63, wid = threadIdx.x >> 6;
  int t = blockIdx.x * 4 + wid;
  const float* xr = x + (size_t)t * DIM + lane * 16;
  float4 x4[4];
#pragma unroll
  for (int q = 0; q < 4; ++q) x4[q] = *(const float4*)(xr + q * 4);
  {  // cast this token's full row to bf16
    bf16* xo = xb + (size_t)t * DIM + lane * 16;
#pragma unroll
    for (int q = 0; q < 4; ++q) {
      bf16x4 o{__float2bfloat16(x4[q].x), __float2bfloat16(x4[q].y),
               __float2bfloat16(x4[q].z), __float2bfloat16(x4[q].w)};
      *reinterpret_cast<bf16x4*>(xo + q * 4) = o;
    }
  }
  float s[NE];
#pragma unroll
  for (int e = 0; e < NE; ++e) {
    const float* wr_ = gw + (size_t)e * DIM + lane * 16;
    float a = 0.f;
#pragma unroll
    for (int q = 0; q < 4; ++q) {
      float4 w4 = *(const float4*)(wr_ + q * 4);
      a += x4[q].x * w4.x + x4[q].y * w4.y + x4[q].z * w4.z + x4[q].w * w4.w;
    }
    s[e] = a;
  }
#pragma unroll
  for (int e = 0; e < NE; ++e)
#pragma unroll
    for (int off = 32; off; off >>= 1) s[e] += __shfl_xor(s[e], off);
  if (lane == 0) {
#pragma unroll
    for (int e = 0; e < NE; ++e) scores[(size_t)t * NE + e] = s[e];
  }
}

// One THREAD per token: sigmoid + top-4 + LDS histogram -> 16 atomics/block.
__global__ __launch_bounds__(256) void topk_hist(const float* __restrict__ scores,
                                                 int* __restrict__ topi,
                                                 float* __restrict__ topw,
                                                 int* __restrict__ counts) {
  __shared__ int h[NE];
  int tid = threadIdx.x;
  int t = blockIdx.x * 256 + tid;
  if (tid < NE) h[tid] = 0;
  __syncthreads();
  float g[NE];
  const float* sr = scores + (size_t)t * NE;
#pragma unroll
  for (int q = 0; q < 4; ++q) {
    float4 v = *(const float4*)(sr + q * 4);
    g[q * 4 + 0] = 1.f / (1.f + expf(-v.x));
    g[q * 4 + 1] = 1.f / (1.f + expf(-v.y));
    g[q * 4 + 2] = 1.f / (1.f + expf(-v.z));
    g[q * 4 + 3] = 1.f / (1.f + expf(-v.w));
  }
  unsigned used = 0;
  int bi[NK]; float bv[NK];
  float sum = 0.f;
#pragma unroll
  for (int j = 0; j < NK; ++j) {        // lax.top_k tie-break: lowest index first
    int best = 0; float v = -1e30f;
#pragma unroll
    for (int e = 0; e < NE; ++e)
      if (!((used >> e) & 1u) && g[e] > v) { v = g[e]; best = e; }
    used |= 1u << best; bi[j] = best; bv[j] = v; sum += v;
  }
  float inv = 1.f / sum;
#pragma unroll
  for (int j = 0; j < NK; ++j) {
    topi[t * NK + j] = bi[j];
    topw[t * NK + j] = bv[j] * inv;
    atomicAdd(&h[bi[j]], 1);
  }
  __syncthreads();
  if (tid < NE) atomicAdd(&counts[tid], h[tid]);
}

// Tiny serial kernel: offsets, 128-row segment list, cursor reset.
__global__ __launch_bounds__(64) void route_small(const int* __restrict__ counts,
                                                  int* __restrict__ offs,
                                                  int* __restrict__ segs,
                                                  int* __restrict__ nseg,
                                                  int* __restrict__ cursor) {
  if (threadIdx.x != 0) return;
  int o = 0;
#pragma unroll
  for (int e = 0; e < NE; ++e) { offs[e] = o; cursor[e * 32] = 0; o += counts[e]; }
  int s = 0;
  for (int e = 0; e < NE; ++e)
    for (int m = 0; m < counts[e]; m += 128) segs[s++] = (e << 16) | m;
  nseg[0] = s;
}

// Parallel compaction via per-expert atomic cursor (cacheline-padded).
// Also records pair -> slot for the final gather-reduce.
__global__ __launch_bounds__(256) void scatter_pairs(const int* __restrict__ topi,
                                                     const float* __restrict__ topw,
                                                     const int* __restrict__ offs,
                                                     int* __restrict__ cursor,
                                                     int* __restrict__ tok_list,
                                                     float* __restrict__ w_list,
                                                     int* __restrict__ pair_slot) {
  int p = blockIdx.x * 256 + threadIdx.x;
  if (p >= NPAIR) return;
  int e = topi[p];
  int rank = atomicAdd(&cursor[e * 32], 1);
  int slot = offs[e] + rank;
  tok_list[slot] = p >> 2;   // token id
  w_list[slot] = topw[p];
  pair_slot[p] = slot;
}

// ---------------- fused up-projection: shared + routed ----------------
// 128x256 tile, 8 waves (2Mx4N), 48 KB LDS, single-buffered 2-barrier loop.
// B' interleaves W1/W2 rows 16-at-a-time -> z,v in adjacent n-frags.

__global__ __launch_bounds__(512, 4) void up_all(
    const bf16* __restrict__ xb, const bf16* __restrict__ wsinT,
    const bf16* __restrict__ vsinT, const bf16* __restrict__ ewinT,
    const bf16* __restrict__ evinT, const int* __restrict__ tok_list,
    const float* __restrict__ w_list, const int* __restrict__ counts,
    const int* __restrict__ offs, const int* __restrict__ segs,
    const int* __restrict__ nseg, bf16* __restrict__ hsb,
    bf16* __restrict__ hre) {
  int bid = blockIdx.x;
  int j = (bid & 7) * (UP_GRID / 8) + (bid >> 3);  // XCD-chunked job swizzle
  int nj = 128 + 4 * nseg[0];
  if (j >= nj) return;
  int tid = threadIdx.x, lane = tid & 63, wid = tid >> 6;
  int wr = wid >> 2, wc = wid & 3;

  bool is_shared = (j < 128);
  int m0, n0, cnt = TOK, off_e = 0;
  const bf16 *w1, *w2;
  if (is_shared) {
    m0 = (j >> 3) * 128; n0 = j & 7;
    w1 = wsinT; w2 = vsinT;
  } else {
    int r = j - 128;
    int sv = segs[r >> 2]; n0 = r & 3;
    int e = sv >> 16; m0 = sv & 0xffff;
    cnt = counts[e]; off_e = offs[e];
    w1 = ewinT + (size_t)e * HID * DIM;
    w2 = evinT + (size_t)e * HID * DIM;
  }

  const bf16* ap[2]; const bf16* bp[4];
#pragma unroll
  for (int i = 0; i < 2; ++i) {
    int row = (i * 512 + tid) >> 3;  // 0..127
    int gr = is_shared ? (m0 + row) : tok_list[off_e + min(m0 + row, cnt - 1)];
    ap[i] = xb + (size_t)gr * DIM;
  }
#pragma unroll
  for (int i = 0; i < 4; ++i) {
    int r = (i * 512 + tid) >> 3;    // B'-row 0..255
    int ridx = n0 * 128 + (r >> 5) * 16 + (r & 15);
    bp[i] = ((r & 16) ? w2 : w1) + (size_t)ridx * DIM;
  }

  __shared__ alignas(16) bf16 As[128 * 64], Bs[256 * 64];
  f32x4 acc[4][4];
  f32x4 z4 = {0.f, 0.f, 0.f, 0.f};
#pragma unroll
  for (int m = 0; m < 4; ++m)
#pragma unroll
    for (int q = 0; q < 4; ++q) acc[m][q] = z4;

  for (int k0 = 0; k0 < DIM; k0 += 64) {
    __syncthreads();
    stage_p<2>(ap, k0, As, tid);
    stage_p<4>(bp, k0, Bs, tid);
    __syncthreads();
#pragma unroll
    for (int ks = 0; ks < 2; ++ks) {
      int r16 = lane & 15, kc = (ks << 2) + (lane >> 4);
      s16x8 a[4];
#pragma unroll
      for (int m = 0; m < 4; ++m) a[m] = frag(As, wr * 64 + m * 16 + r16, kc);
#pragma unroll
      for (int q = 0; q < 4; ++q) {
        s16x8 b = frag(Bs, wc * 64 + q * 16 + r16, kc);
#pragma unroll
        for (int m = 0; m < 4; ++m) acc[m][q] = MFMA(a[m], b, acc[m][q]);
      }
    }
  }
#pragma unroll
  for (int m = 0; m < 4; ++m)
#pragma unroll
    for (int q = 0; q < 4; q += 2) {
      int c = n0 * 128 + (wc * 2 + (q >> 1)) * 16 + (lane & 15);
#pragma unroll
      for (int i = 0; i < 4; ++i) {
        int r = wr * 64 + m * 16 + (lane >> 4) * 4 + i;
        float z = acc[m][q][i], v = acc[m][q + 1][i];
        float h = z / (1.f + __expf(-z)) * v;
        if (is_shared) {
          hsb[(size_t)(m0 + r) * NHS + c] = __float2bfloat16(h);
        } else {
          int gr = m0 + r;
          if (gr < cnt)
            hre[(size_t)(off_e + gr) * HID + c] =
                __float2bfloat16(h * w_list[off_e + gr]);
        }
      }
    }
}

// ---------------- fused down-projection: NO atomics ----------------
// Shared jobs plain-store their unique 128x256 out tile (covers out exactly
// once -> no memset). Routed jobs plain-store bf16 per-pair rows into
// hrd[slot][DIM] (aliases dead evinT, exactly 16 MiB). finish_add reduces.
// Job space: [0,64): shared (16 m x 4 n), K=1024.
//            [64, 64+4*nseg): routed seg x 4 n-tiles, K=512.

__global__ __launch_bounds__(512, 4) void down_all(
    const bf16* __restrict__ hsb, const bf16* __restrict__ wsoutT,
    const bf16* __restrict__ hre, const bf16* __restrict__ ewoutT,
    const int* __restrict__ tok_list, const int* __restrict__ counts,
    const int* __restrict__ offs, const int* __restrict__ segs,
    const int* __restrict__ nseg, float* __restrict__ out,
    bf16* __restrict__ hrd) {
  int bid = blockIdx.x;
  int j = (bid & 7) * (DN_GRID / 8) + (bid >> 3);
  int nj = 64 + 4 * nseg[0];
  if (j >= nj) return;
  int tid = threadIdx.x, lane = tid & 63, wid = tid >> 6;
  int wr = wid >> 2, wc = wid & 3;

  bool is_shared = (j < 64);
  int m0, n0, cnt = TOK, off_e = 0, K, ldA, ldB;
  const bf16 *Abase, *Bbase;
  if (is_shared) {
    m0 = (j >> 2) * 128; n0 = j & 3;
    Abase = hsb; ldA = NHS; K = NHS;
    Bbase = wsoutT; ldB = NHS;
  } else {
    int r = j - 64;
    int sv = segs[r >> 2]; n0 = r & 3;
    int e = sv >> 16; m0 = sv & 0xffff;
    cnt = counts[e]; off_e = offs[e];
    Abase = hre + (size_t)off_e * HID; ldA = HID; K = HID;
    Bbase = ewoutT + (size_t)e * DIM * HID; ldB = HID;
  }

  const bf16* ap[2]; const bf16* bp[4];
#pragma unroll
  for (int i = 0; i < 2; ++i) {
    int row = (i * 512 + tid) >> 3;  // 0..127
    int gr = is_shared ? (m0 + row) : min(m0 + row, cnt - 1);
    ap[i] = Abase + (size_t)gr * ldA;
  }
#pragma unroll
  for (int i = 0; i < 4; ++i) {
    int r = (i * 512 + tid) >> 3;    // 0..255
    bp[i] = Bbase + (size_t)(n0 * 256 + r) * ldB;
  }

  __shared__ alignas(16) bf16 As[128 * 64], Bs[256 * 64];
  f32x4 acc[4][4];
  f32x4 z4 = {0.f, 0.f, 0.f, 0.f};
#pragma unroll
  for (int m = 0; m < 4; ++m)
#pragma unroll
    for (int q = 0; q < 4; ++q) acc[m][q] = z4;

  int NT = K / 64;
  for (int kt = 0; kt < NT; ++kt) {
    int k0 = kt * 64;
    __syncthreads();
    stage_p<2>(ap, k0, As, tid);
    stage_p<4>(bp, k0, Bs, tid);
    __syncthreads();
#pragma unroll
    for (int ks = 0; ks < 2; ++ks) {
      int r16 = lane & 15, kc = (ks << 2) + (lane >> 4);
      s16x8 a[4];
#pragma unroll
      for (int m = 0; m < 4; ++m) a[m] = frag(As, wr * 64 + m * 16 + r16, kc);
#pragma unroll
      for (int q = 0; q < 4; ++q) {
        s16x8 b = frag(Bs, wc * 64 + q * 16 + r16, kc);
#pragma unroll
        for (int m = 0; m < 4; ++m) acc[m][q] = MFMA(a[m], b, acc[m][q]);
      }
    }
  }
#pragma unroll
  for (int m = 0; m < 4; ++m)
#pragma unroll
    for (int q = 0; q < 4; ++q) {
      int c = n0 * 256 + wc * 64 + q * 16 + (lane & 15);
#pragma unroll
      for (int i = 0; i < 4; ++i) {
        int r = wr * 64 + m * 16 + (lane >> 4) * 4 + i;
        if (is_shared) {
          out[(size_t)(m0 + r) * DIM + c] = acc[m][q][i];
        } else {
          int gr = m0 + r;
          if (gr < cnt)
            hrd[(size_t)(off_e + gr) * DIM + c] = __float2bfloat16(acc[m][q][i]);
        }
      }
    }
}

// ---------------- final gather-reduce: out[t] += sum of 4 routed rows -------
// One thread per 8 output cols. hrd rows located via pair_slot.

__global__ __launch_bounds__(256) void finish_add(const bf16* __restrict__ hrd,
                                                  const int* __restrict__ pair_slot,
                                                  float* __restrict__ out) {
  int idx = blockIdx.x * 256 + threadIdx.x;
  int t = idx >> 7;            // DIM/8 = 128 chunks per token
  int c0 = (idx & 127) * 8;
  int4 s4 = *(const int4*)(pair_slot + t * 4);
  float acc[8];
  float* o = out + (size_t)t * DIM + c0;
#pragma unroll
  for (int k = 0; k < 8; ++k) acc[k] = o[k];
  int sl[4] = {s4.x, s4.y, s4.z, s4.w};
#pragma unroll
  for (int j = 0; j < 4; ++j) {
    s16x8 v = *(const s16x8*)(hrd + (size_t)sl[j] * DIM + c0);
#pragma unroll
    for (int k = 0; k < 8; ++k) acc[k] += b2f(v[k]);
  }
#pragma unroll
  for (int k = 0; k < 8; ++k) o[k] = acc[k];
}

// ---------------- launcher ----------------

extern "C" void kernel_launch(void* const* d_in, const int* in_sizes, int n_in,
                              void* d_out, int out_size, void* d_ws, size_t ws_size,
                              hipStream_t stream) {
  const float* x      = (const float*)d_in[0];
  const float* gw     = (const float*)d_in[1];
  const float* ws_in  = (const float*)d_in[2];
  const float* vs_in  = (const float*)d_in[3];
  const float* ws_out = (const float*)d_in[4];
  const float* e_win  = (const float*)d_in[5];
  const float* e_vin  = (const float*)d_in[6];
  const float* e_wout = (const float*)d_in[7];
  float* out = (float*)d_out;

  // Workspace layout, peak ~52.7 MB (validated fits in rounds 2-8).
  char* p = (char*)d_ws;
  bf16* xb     = (bf16*)p;  p += (size_t)TOK * DIM * 2;            // 4 MB
  bf16* wsinT  = (bf16*)p;                                         // 2 MB
  bf16* wsoutT = wsinT;                                            // reused after up_all
  p += (size_t)NHS * DIM * 2;
  bf16* vsinT  = (bf16*)p;  p += (size_t)NHS * DIM * 2;            // 2 MB
  bf16* hsb    = (bf16*)p;  p += (size_t)TOK * NHS * 2;            // 4 MB
  bf16* ewinT  = (bf16*)p;                                         // 16 MB
  bf16* ewoutT = ewinT;                                            // reused after up_all
  p += (size_t)NE * DIM * HID * 2;
  bf16* evinT  = (bf16*)p;                                         // 16 MB
  bf16* hrd    = evinT;  // routed down-proj rows; NPAIR*DIM*2 = exactly 16 MiB
  p += (size_t)NE * DIM * HID * 2;
  bf16* hre    = (bf16*)p;  p += (size_t)(NPAIR + 128) * HID * 2;  // 8.25 MB
  int*   topi      = (int*)p;    p += (size_t)NPAIR * 4;
  float* topw      = (float*)p;  p += (size_t)NPAIR * 4;
  int*   tok_list  = (int*)p;    p += (size_t)NPAIR * 4;
  float* w_list    = (float*)p;  p += (size_t)NPAIR * 4;
  int*   pair_slot = (int*)p;    p += (size_t)NPAIR * 4;
  float* scores    = (float*)p;  p += (size_t)TOK * NE * 4;        // 128 KB
  int*   counts    = (int*)p;    p += 64;
  int*   offs      = (int*)p;    p += 64;
  int*   cursor    = (int*)p;    p += NE * 32 * 4;                 // 1 line/expert
  int*   segs      = (int*)p;    p += 128 * 4;   // worst case 80 segs
  int*   nseg      = (int*)p;    p += 64;

  hipMemsetAsync(counts, 0, NE * sizeof(int), stream);
  gate_scores<<<TOK / 4, 256, 0, stream>>>(x, gw, xb, scores);
  topk_hist<<<TOK / 256, 256, 0, stream>>>(scores, topi, topw, counts);
  route_small<<<1, 64, 0, stream>>>(counts, offs, segs, nseg, cursor);
  scatter_pairs<<<NPAIR / 256, 256, 0, stream>>>(topi, topw, offs, cursor,
                                                 tok_list, w_list, pair_slot);

  prep1<<<18432, 256, 0, stream>>>(ws_in, vs_in, e_win, e_vin,
                                   wsinT, vsinT, ewinT, evinT);

  up_all<<<UP_GRID, 512, 0, stream>>>(xb, wsinT, vsinT, ewinT, evinT, tok_list,
                                      w_list, counts, offs, segs, nseg, hsb, hre);

  // ws_out/e_wout transposes overwrite wsinT/ewinT (dead after up_all).
  prep2<<<9216, 256, 0, stream>>>(ws_out, e_wout, wsoutT, ewoutT);

  // down: shared jobs plain-store out; routed jobs plain-store hrd (=evinT).
  down_all<<<DN_GRID, 512, 0, stream>>>(hsb, wsoutT, hre, ewoutT, tok_list,
                                        counts, offs, segs, nseg, out, hrd);
  finish_add<<<TOK * DIM / 8 / 256, 256, 0, stream>>>(hrd, pair_slot, out);
}